// Round 7
// baseline (205.754 us; speedup 1.0000x reference)
//
#include <hip/hip_runtime.h>
#include <hip/hip_fp16.h>
#include <cstdint>

#define D 128
#define BLK 256

constexpr float MINN    = 1e-15f;
constexpr float ATCLIP  = 1.0f - 1e-7f;
constexpr float BALLEPS = 4e-3f;

typedef _Float16 f16x8 __attribute__((ext_vector_type(8)));
typedef float    f32x4 __attribute__((ext_vector_type(4)));

union H4 { _Float16 h[4]; uint2 u2; };
union H8 { _Float16 h[8]; uint4 u4; };

typedef __attribute__((address_space(1))) const void gas_v;
typedef __attribute__((address_space(3))) void las_v;

__device__ __forceinline__ float red64(float v) {
    v += __shfl_xor(v, 1, 64);
    v += __shfl_xor(v, 2, 64);
    v += __shfl_xor(v, 4, 64);
    v += __shfl_xor(v, 8, 64);
    v += __shfl_xor(v, 16, 64);
    v += __shfl_xor(v, 32, 64);
    return v;
}

__device__ __forceinline__ int red64i(int v) {
    v += __shfl_xor(v, 1, 64);
    v += __shfl_xor(v, 2, 64);
    v += __shfl_xor(v, 4, 64);
    v += __shfl_xor(v, 8, 64);
    v += __shfl_xor(v, 16, 64);
    v += __shfl_xor(v, 32, 64);
    return v;
}

__device__ __forceinline__ float red16(float v) {
    v += __shfl_xor(v, 1, 64);
    v += __shfl_xor(v, 2, 64);
    v += __shfl_xor(v, 4, 64);
    v += __shfl_xor(v, 8, 64);
    return v;
}

// fast transcendentals (args here are small: |x| < ~16)
__device__ __forceinline__ float tanh_fast(float x) {   // x >= 0
    float e = __expf(2.f * fminf(x, 15.f));
    return __fdividef(e - 1.f, e + 1.f);
}
__device__ __forceinline__ float artanh_fast(float x) { // x in [0, 1)
    x = fminf(x, ATCLIP);
    return 0.5f * __logf(__fdividef(1.f + x, 1.f - x));
}

// ---------------------------------------------------------------------------
// Kernel 0: blocks 0..7  : W fp32 -> fp16, fragment-order layout.
//           blocks 8..   : zero cnt[] + lookback[] region.
// Wh[f*1024 + r*8 + j] = (fp16) W[r][f*8+j],  f = k-chunk 0..15, r = row 0..127.
// ---------------------------------------------------------------------------
__global__ __launch_bounds__(256) void k_prep(const float* __restrict__ W,
                                              _Float16* __restrict__ Wh,
                                              int* __restrict__ zero, int zeroInts)
{
    const int t = threadIdx.x;
    const int bid = blockIdx.x;
    if (bid < 8) {
        int i = bid * 256 + t;                // 0..2047
        int f = i >> 7;
        int r = i & 127;
        const float4* src = (const float4*)(W + r * 128 + f * 8);
        float4 v0 = src[0], v1 = src[1];
        H8 u;
        u.h[0] = (_Float16)v0.x; u.h[1] = (_Float16)v0.y;
        u.h[2] = (_Float16)v0.z; u.h[3] = (_Float16)v0.w;
        u.h[4] = (_Float16)v1.x; u.h[5] = (_Float16)v1.y;
        u.h[6] = (_Float16)v1.z; u.h[7] = (_Float16)v1.w;
        *(uint4*)(Wh + i * 8) = u.u4;
    } else {
        int i = (bid - 8) * 256 + t;          // int4 index
        int base = i * 4;
        if (base + 3 < zeroInts) {
            *(int4*)(zero + base) = make_int4(0, 0, 0, 0);
        } else if (base < zeroInts) {
            for (int k = base; k < zeroInts; ++k) zero[k] = 0;
        }
    }
}

// ---------------------------------------------------------------------------
// Kernel 1 (MFMA): h_t = logmap0( mobius_add( mobius_matvec(W,x), expmap0(b) ) )
// Two 64-node tiles per block (128 nodes), 4 waves, 32 KB LDS (r3-proven
// pipeline, measured <=41.3 us): tile0 via async global_load_lds with a
// per-wave counted vmcnt fence; tile1 register-prefetched at t=0 so its HBM
// latency hides under tile0's compute; mid-kernel barrier is raw s_barrier +
// lgkmcnt only (no store-ack drain).
// In-degree histogram in the TAIL with phase-separated memory ops: all dst
// loads issued (parallel round-trip), then all atomics in flight, then
// coalesced rank stores -> ~2 serial fabric round-trips instead of ~6.
// Transient tail registers only (r4's persistent preload cost occupancy).
// ---------------------------------------------------------------------------
__global__ __launch_bounds__(BLK) void k_node_mfma(
    const float* __restrict__ x, const _Float16* __restrict__ Wh,
    const float* __restrict__ b, uint2* __restrict__ ht, int N,
    const int* __restrict__ ei, int* __restrict__ cnt,
    int* __restrict__ rank, int E, int eslice, int use_rank)
{
    __shared__ float xs[64 * 128];      // 32768 B, swizzled chunks (overlaid later)

    const int t     = threadIdx.x;
    const int lane  = t & 63;
    const int w     = t >> 6;
    const int node0 = blockIdx.x * 128;

    // ---- vmem group 1 (oldest): bias
    float2 b2 = ((const float2*)b)[lane];     // 64 lanes x 2 = all 128 dims
    __builtin_amdgcn_sched_barrier(0);

    // ---- vmem group 2: async DMA tile0 -> own wave's LDS region (8 x 1KB)
#pragma unroll
    for (int i = 0; i < 8; ++i) {
        int P      = (w * 8 + i) * 64 + lane;       // LDS chunk slot
        int node   = P >> 5;
        int q      = (P & 31) ^ (node & 7);         // swizzle: slot p holds chunk p^(n&7)
        int node_g = min(node0 + node, N - 1);      // clamp OOB tail
        const float* src = x + (size_t)node_g * 128 + q * 4;
        char* dst = (char*)xs + (size_t)(w * 8 + i) * 1024;   // wave-uniform base
        __builtin_amdgcn_global_load_lds((gas_v*)src, (las_v*)dst, 16, 0, 0);
    }
    __builtin_amdgcn_sched_barrier(0);

    // ---- vmem group 3 (newest): register-prefetch tile1, same chunk layout
    f32x4 rv[8];
#pragma unroll
    for (int i = 0; i < 8; ++i) {
        int P      = (w * 8 + i) * 64 + lane;
        int node   = P >> 5;
        int q      = (P & 31) ^ (node & 7);
        int node_g = min(node0 + 64 + node, N - 1);
        rv[i] = *(const f32x4*)(x + (size_t)node_g * 128 + q * 4);
    }
    __builtin_amdgcn_sched_barrier(0);

    // ---- bscale for p = expmap0(b) = bscale*b (compiler waits b only)
    float pb  = fmaf(b2.x, b2.x, b2.y * b2.y);
    float bn2 = red64(pb);
    float bnc    = fmaxf(sqrtf(bn2), MINN);
    float bscale = __fdividef(tanh_fast(bnc), bnc);
    const float y2 = bscale * bscale * bn2;   // ||p||^2

    const int c = lane & 15;        // node within wave-tile / W row within m-tile
    const int g = lane >> 4;        // quad
    const int bnode = w * 16 + c;
    const int sw    = bnode & 7;
    const float* xrow = &xs[bnode * 128];
    const float4* b4  = (const float4*)b;
    uint2* lout = (uint2*)((char*)xs + (size_t)w * 8192);   // own wave region

    auto do_tile = [&]() {
        f32x4 Cf[8];
#pragma unroll
        for (int mt = 0; mt < 8; ++mt) Cf[mt] = (f32x4){0.f, 0.f, 0.f, 0.f};
        float px = 0.f;               // fp32 ||x||^2 partial (this lane's 32 dims)

#pragma unroll
        for (int s = 0; s < 4; ++s) {
            int q0 = s * 8 + g * 2;
            f32x4 lo = *(const f32x4*)&xrow[(q0 ^ sw) * 4];
            f32x4 hi = *(const f32x4*)&xrow[((q0 + 1) ^ sw) * 4];
            px = fmaf(lo[0], lo[0], px); px = fmaf(lo[1], lo[1], px);
            px = fmaf(lo[2], lo[2], px); px = fmaf(lo[3], lo[3], px);
            px = fmaf(hi[0], hi[0], px); px = fmaf(hi[1], hi[1], px);
            px = fmaf(hi[2], hi[2], px); px = fmaf(hi[3], hi[3], px);
            f16x8 Bf;
            Bf[0] = (_Float16)lo[0]; Bf[1] = (_Float16)lo[1];
            Bf[2] = (_Float16)lo[2]; Bf[3] = (_Float16)lo[3];
            Bf[4] = (_Float16)hi[0]; Bf[5] = (_Float16)hi[1];
            Bf[6] = (_Float16)hi[2]; Bf[7] = (_Float16)hi[3];
            const _Float16* wp = Wh + ((s * 4 + g) << 10) + (c << 3);
#pragma unroll
            for (int mt = 0; mt < 8; ++mt) {
                f16x8 Af = *(const f16x8*)&wp[mt << 7];
                Cf[mt] = __builtin_amdgcn_mfma_f32_16x16x32_f16(Af, Bf, Cf[mt], 0, 0, 0);
            }
        }
        // lane holds mx[mt*16 + g*4 + r][tile + bnode] in Cf[mt][r]

        // per-node epilogue: p = bscale*b -> <mx,p> = bscale*<mx,b>
        float pm = 0.f, pdb = 0.f;
#pragma unroll
        for (int mt = 0; mt < 8; ++mt) {
            float4 bv = b4[mt * 4 + g];
            pm  = fmaf(Cf[mt][0], Cf[mt][0], pm);
            pm  = fmaf(Cf[mt][1], Cf[mt][1], pm);
            pm  = fmaf(Cf[mt][2], Cf[mt][2], pm);
            pm  = fmaf(Cf[mt][3], Cf[mt][3], pm);
            pdb = fmaf(Cf[mt][0], bv.x, pdb);
            pdb = fmaf(Cf[mt][1], bv.y, pdb);
            pdb = fmaf(Cf[mt][2], bv.z, pdb);
            pdb = fmaf(Cf[mt][3], bv.w, pdb);
        }
        float xn2 = px;
        xn2 += __shfl_xor(xn2, 16); xn2 += __shfl_xor(xn2, 32);   // ||x||^2
        pm  += __shfl_xor(pm, 16);  pm  += __shfl_xor(pm, 32);    // ||mx||^2
        pdb += __shfl_xor(pdb, 16); pdb += __shfl_xor(pdb, 32);   // <mx, b>
        float pd = bscale * pdb;                                  // <mx, p>

        float xn      = fmaxf(sqrtf(xn2), MINN);
        float mxn_raw = sqrtf(pm);
        float mxn     = fmaxf(mxn_raw, MINN);
        float alpha   = __fdividef(tanh_fast(__fdividef(mxn, xn) * artanh_fast(xn)), mxn);
        if (mxn_raw <= 1e-10f) alpha = 0.f;     // zero-row guard

        float x2  = alpha * alpha * pm;
        float xy  = alpha * pd;
        float den = fmaxf(fmaf(x2, y2, 1.f + 2.f * xy), MINN);
        float ca  = __fdividef((1.f + 2.f * xy + y2) * alpha, den);
        float cb  = __fdividef(1.f - x2, den);

        float hn2 = ca * ca * pm + 2.f * ca * cb * pd + cb * cb * y2;
        float hn  = fmaxf(sqrtf(hn2), MINN);
        float lsc = __fdividef(artanh_fast(hn), hn);
        float s1  = lsc * ca;
        float s2b = lsc * cb * bscale;

        // pack to fp16 via LDS transpose into OWN wave region (in-wave LDS
        // ordering: reads above retire before these writes -> no barrier)
#pragma unroll
        for (int mt = 0; mt < 8; ++mt) {
            float4 bv = b4[mt * 4 + g];
            H4 u;
            u.h[0] = (_Float16)fmaf(s1, Cf[mt][0], s2b * bv.x);
            u.h[1] = (_Float16)fmaf(s1, Cf[mt][1], s2b * bv.y);
            u.h[2] = (_Float16)fmaf(s1, Cf[mt][2], s2b * bv.z);
            u.h[3] = (_Float16)fmaf(s1, Cf[mt][3], s2b * bv.w);
            lout[c * 33 + mt * 4 + g] = u.u2;
        }
    };

    auto copyout = [&](int tb) {
#pragma unroll
        for (int it = 0; it < 8; ++it) {
            int lin  = it * BLK + t;        // 2048 uint2
            int node = lin >> 5;
            int col  = lin & 31;
            int gn   = tb + node;
            if (gn < N) {
                const uint2* lsrc = (const uint2*)((const char*)xs + (size_t)(node >> 4) * 8192);
                ht[(size_t)gn * 32 + col] = lsrc[(node & 15) * 33 + col];
            }
        }
    };

    // ---- tile0 ready for THIS wave only (drains b+DMA; rv stays in flight)
    asm volatile("s_waitcnt vmcnt(8)" ::: "memory");
    __builtin_amdgcn_sched_barrier(0);

    do_tile();
    __syncthreads();                  // all waves' transposes visible
    copyout(node0);

    // all waves done READING xs; avoid vmcnt(0) store-ack drain: raw barrier
    asm volatile("s_waitcnt lgkmcnt(0)" ::: "memory");
    __builtin_amdgcn_sched_barrier(0);
    __builtin_amdgcn_s_barrier();
    __builtin_amdgcn_sched_barrier(0);

    // ---- ds_write tile1 from prefetch regs into own region
#pragma unroll
    for (int i = 0; i < 8; ++i) {
        float* dst = (float*)((char*)xs + (size_t)(w * 8 + i) * 1024 + (size_t)lane * 16);
        *(f32x4*)dst = rv[i];
    }
    do_tile();
    __syncthreads();
    copyout(node0 + 64);

    // ---- in-degree histogram TAIL, phase-separated for minimal round-trips:
    // (1) issue all dst loads (parallel), (2) all atomics in flight,
    // (3) coalesced rank stores. Transient registers only.
    __builtin_amdgcn_sched_barrier(0);
    {
        const int e0 = blockIdx.x * eslice;
        int ed0 = -1, ed1 = -1, ed2 = -1;
        int ee0 = e0 + 0 * BLK + t;
        int ee1 = e0 + 1 * BLK + t;
        int ee2 = e0 + 2 * BLK + t;
        if (0 * BLK + t < eslice && ee0 < E) ed0 = ei[E + ee0];
        if (1 * BLK + t < eslice && ee1 < E) ed1 = ei[E + ee1];
        if (2 * BLK + t < eslice && ee2 < E) ed2 = ei[E + ee2];
        int r0 = 0, r1 = 0, r2 = 0;
        if (ed0 >= 0) r0 = atomicAdd(&cnt[ed0], 1);
        if (ed1 >= 0) r1 = atomicAdd(&cnt[ed1], 1);
        if (ed2 >= 0) r2 = atomicAdd(&cnt[ed2], 1);
        if (use_rank) {
            if (ed0 >= 0) rank[ee0] = r0;
            if (ed1 >= 0) rank[ee1] = r1;
            if (ed2 >= 0) rank[ee2] = r2;
        }
        // remainder (only if eslice > 3*BLK; not hit at current shapes)
        for (int i = 3 * BLK + t; i < eslice; i += BLK) {
            int e = e0 + i;
            if (e < E) {
                int r = atomicAdd(&cnt[ei[E + e]], 1);
                if (use_rank) rank[e] = r;
            }
        }
    }
}

// ---------------------------------------------------------------------------
// Single-pass scan with parallel decoupled lookback: ptr[n] = global exclusive
// prefix of cnt. lb[bid] = (flag<<32)|value; flag 1 = aggregate, 2 = inclusive
// prefix. All blocks co-resident (nc ~ 98 << CU count); wave 3 does a 64-wide
// parallel lookback. Agent-scope atomics for cross-XCD safety.
// ---------------------------------------------------------------------------
__global__ __launch_bounds__(256) void k_scan(
    const int* __restrict__ cnt, int* __restrict__ ptr,
    unsigned long long* __restrict__ lb, int N)
{
    __shared__ int s[256];
    __shared__ int sbase;
    const int t   = threadIdx.x;
    const int bid = blockIdx.x;
    const int lane = t & 63;
    const int w    = t >> 6;

    int base = bid * 1024 + t * 4;
    int v0 = 0, v1 = 0, v2 = 0, v3 = 0;
    if (base + 3 < N) {
        int4 q = *(const int4*)&cnt[base];
        v0 = q.x; v1 = q.y; v2 = q.z; v3 = q.w;
    } else {
        if (base + 0 < N) v0 = cnt[base + 0];
        if (base + 1 < N) v1 = cnt[base + 1];
        if (base + 2 < N) v2 = cnt[base + 2];
        if (base + 3 < N) v3 = cnt[base + 3];
    }
    int sum = v0 + v1 + v2 + v3;
    s[t] = sum;
    __syncthreads();
    for (int off = 1; off < 256; off <<= 1) {
        int xv = (t >= off) ? s[t - off] : 0;
        __syncthreads();
        s[t] += xv;
        __syncthreads();
    }
    int excl  = s[t] - sum;
    int total = s[255];

    if (t == 255) {
        unsigned long long pkt =
            ((unsigned long long)((bid == 0) ? 2u : 1u) << 32) | (unsigned)total;
        __hip_atomic_store(&lb[bid], pkt, __ATOMIC_RELEASE, __HIP_MEMORY_SCOPE_AGENT);
        if (bid == 0) sbase = 0;
    }

    if (bid > 0 && w == 3) {
        int exclb = 0;
        int j = bid - 1;
        while (true) {
            int idx = j - lane;
            unsigned f = 0; int v = 0;
            if (idx >= 0) {
                unsigned long long p;
                do {
                    p = __hip_atomic_load(&lb[idx], __ATOMIC_ACQUIRE, __HIP_MEMORY_SCOPE_AGENT);
                    f = (unsigned)(p >> 32);
                } while (f == 0);
                v = (int)(unsigned)(p & 0xffffffffu);
            }
            unsigned long long m2 = __ballot(f == 2u);
            if (m2) {
                int Lstop = __ffsll((long long)m2) - 1;   // nearest flag-2 predecessor
                int contrib = (lane <= Lstop) ? v : 0;
                exclb += red64i(contrib);
                break;
            } else {
                exclb += red64i((idx >= 0) ? v : 0);
                j -= 64;
            }
        }
        if (lane == 0) {
            unsigned long long pkt2 =
                ((unsigned long long)2u << 32) | (unsigned)(exclb + total);
            __hip_atomic_store(&lb[bid], pkt2, __ATOMIC_RELEASE, __HIP_MEMORY_SCOPE_AGENT);
            sbase = exclb;
        }
    }
    __syncthreads();

    int r = excl + sbase;
    if (base + 0 < N) ptr[base + 0] = r; r += v0;
    if (base + 1 < N) ptr[base + 1] = r; r += v1;
    if (base + 2 < N) ptr[base + 2] = r; r += v2;
    if (base + 3 < N) ptr[base + 3] = r;
}

// scatter, rank-based (no atomics): pos = global excl start + per-edge rank.
// Nontemporal store: sorted is written once, read once later -> skip L2 alloc.
__global__ __launch_bounds__(256) void k_scatter_rank(
    const int* __restrict__ ei, const float* __restrict__ ew,
    const int* __restrict__ ptr, const int* __restrict__ rank,
    int2* __restrict__ sorted, int E)
{
    int e = blockIdx.x * 256 + threadIdx.x;
    if (e >= E) return;
    int src = ei[e];
    int dst = ei[E + e];
    float w = ew[e];
    int pos = ptr[dst] + rank[e];
    long long v = ((long long)__float_as_int(w) << 32) | (unsigned)(src << 8);
    __builtin_nontemporal_store(v, (long long*)&sorted[pos]);
}

// fallback scatter with atomics (destroys ptr -> ptr becomes inclusive end)
__global__ __launch_bounds__(256) void k_scatter_atomic(
    const int* __restrict__ ei, const float* __restrict__ ew,
    int* __restrict__ ptr, int2* __restrict__ sorted, int E)
{
    int e = blockIdx.x * 256 + threadIdx.x;
    if (e >= E) return;
    int src = ei[e];
    int dst = ei[E + e];
    float w = ew[e];
    int pos = atomicAdd(&ptr[dst], 1);
    sorted[pos] = make_int2(src << 8, __float_as_int(w));
}

// ---------------------------------------------------------------------------
// Fused aggregation + epilogue: 16 lanes per node (4 nodes per wave64).
// Lane owns dims 8*li .. 8*li+7 (uint4 = 16 B per gathered row).
// 4-edge unrolled gather for memory-level parallelism. Nontemporal out
// stores (out is never re-read).
// rmode=1: ptr is exclusive start (rank path). rmode=0: ptr is inclusive end.
// ---------------------------------------------------------------------------
__global__ __launch_bounds__(256) void k_agg_final(
    const char* __restrict__ htb, const int* __restrict__ ptr,
    const int* __restrict__ cnt, const int2* __restrict__ sorted,
    const float* __restrict__ a_in, float* __restrict__ out, int N, int rmode)
{
    const int t   = threadIdx.x;
    const int li  = t & 15;          // lane within 16-lane group
    const int grp = t >> 4;          // group within block (0..15)
    const int n   = blockIdx.x * 16 + grp;
    if (n >= N) return;
    const float a = a_in[0];

    H8 own; own.u4 = *(const uint4*)(htb + (size_t)n * 256 + li * 16);
    float acc[8];
#pragma unroll
    for (int k = 0; k < 8; ++k) acc[k] = (float)own.h[k];

    int basep = ptr[n];
    int cn    = cnt[n];
    int s0    = rmode ? basep : basep - cn;
    int e0    = s0 + cn;

    const int lioff = li * 16;
    int j = s0;
    for (; j + 4 <= e0; j += 4) {
        int2 d0 = sorted[j];
        int2 d1 = sorted[j + 1];
        int2 d2 = sorted[j + 2];
        int2 d3 = sorted[j + 3];
        H8 g0, g1, g2, g3;
        g0.u4 = *(const uint4*)(htb + (unsigned)d0.x + lioff);
        g1.u4 = *(const uint4*)(htb + (unsigned)d1.x + lioff);
        g2.u4 = *(const uint4*)(htb + (unsigned)d2.x + lioff);
        g3.u4 = *(const uint4*)(htb + (unsigned)d3.x + lioff);
        float w0 = __int_as_float(d0.y);
        float w1 = __int_as_float(d1.y);
        float w2 = __int_as_float(d2.y);
        float w3 = __int_as_float(d3.y);
#pragma unroll
        for (int k = 0; k < 8; ++k) acc[k] = fmaf((float)g0.h[k], w0, acc[k]);
#pragma unroll
        for (int k = 0; k < 8; ++k) acc[k] = fmaf((float)g1.h[k], w1, acc[k]);
#pragma unroll
        for (int k = 0; k < 8; ++k) acc[k] = fmaf((float)g2.h[k], w2, acc[k]);
#pragma unroll
        for (int k = 0; k < 8; ++k) acc[k] = fmaf((float)g3.h[k], w3, acc[k]);
    }
    for (; j < e0; ++j) {
        int2 d = sorted[j];
        H8 g; g.u4 = *(const uint4*)(htb + (unsigned)d.x + lioff);
        float w = __int_as_float(d.y);
#pragma unroll
        for (int k = 0; k < 8; ++k) acc[k] = fmaf((float)g.h[k], w, acc[k]);
    }

    // h2_t = acc; PReLU
    float pv = 0.f;
#pragma unroll
    for (int k = 0; k < 8; ++k) {
        float v = acc[k];
        v = (v >= 0.f) ? v : a * v;
        acc[k] = v;
        pv = fmaf(v, v, pv);
    }
    float m2 = red16(pv);
    float rc = fmaxf(sqrtf(m2), MINN);
    float te = tanh_fast(rc);
    const float maxn = 1.0f - BALLEPS;
    float fsc = __fdividef(fminf(fmaxf(te, MINN), maxn), rc);

    f32x4 o0 = {fsc * acc[0], fsc * acc[1], fsc * acc[2], fsc * acc[3]};
    f32x4 o1 = {fsc * acc[4], fsc * acc[5], fsc * acc[6], fsc * acc[7]};
    f32x4* orow = (f32x4*)(out + (size_t)n * D);
    __builtin_nontemporal_store(o0, &orow[li * 2 + 0]);
    __builtin_nontemporal_store(o1, &orow[li * 2 + 1]);
}

// ---------------------------------------------------------------------------
extern "C" void kernel_launch(void* const* d_in, const int* in_sizes, int n_in,
                              void* d_out, int out_size, void* d_ws, size_t ws_size,
                              hipStream_t stream)
{
    const float* x  = (const float*)d_in[0];
    const int*   ei = (const int*)  d_in[1];
    const float* ew = (const float*)d_in[2];
    const float* W  = (const float*)d_in[3];
    const float* b  = (const float*)d_in[4];
    const float* a  = (const float*)d_in[5];
    float* out = (float*)d_out;

    const int N = in_sizes[0] / D;
    const int E = in_sizes[1] / 2;
    const int nc = (N + 1023) / 1024;

    // workspace carve-up
    char* ws = (char*)d_ws;
    size_t HT_B       = (size_t)N * D * 2;          // fp16 h_t
    uint2*              ht  = (uint2*)ws;
    size_t off_cnt    = HT_B;
    int*                cnt = (int*)(ws + off_cnt);
    size_t off_lb     = (off_cnt + (size_t)N * 4 + 15) & ~(size_t)15;
    unsigned long long* lb  = (unsigned long long*)(ws + off_lb);
    size_t off_ptr    = (off_lb + (size_t)nc * 8 + 15) & ~(size_t)15;
    int*                ptr = (int*)(ws + off_ptr);
    size_t off_sorted = (off_ptr + (size_t)N * 4 + 15) & ~(size_t)15;
    int2*               sorted = (int2*)(ws + off_sorted);
    size_t off_wh     = off_sorted + (size_t)E * 8;
    _Float16*           Wh  = (_Float16*)(ws + off_wh);
    size_t off_rank   = off_wh + 32768;
    int*                rank = (int*)(ws + off_rank);
    int use_rank = (ws_size >= off_rank + (size_t)E * 4) ? 1 : 0;

    int zeroInts = (int)((off_ptr - off_cnt) / 4);   // cnt + lb (+pad)
    int zb  = ((zeroInts + 3) / 4 + 255) / 256;
    int nb1 = (N + 127) / 128;                       // two tiles per block
    int eslice = (E + nb1 - 1) / nb1;

    k_prep<<<8 + zb, 256, 0, stream>>>(W, Wh, cnt, zeroInts);
    k_node_mfma<<<nb1, BLK, 0, stream>>>(x, Wh, b, ht, N, ei, cnt,
                                         use_rank ? rank : nullptr, E, eslice, use_rank);
    k_scan<<<nc, 256, 0, stream>>>(cnt, ptr, lb, N);
    if (use_rank)
        k_scatter_rank<<<(E + 255) / 256, 256, 0, stream>>>(ei, ew, ptr, rank, sorted, E);
    else
        k_scatter_atomic<<<(E + 255) / 256, 256, 0, stream>>>(ei, ew, ptr, sorted, E);
    k_agg_final<<<(N + 15) / 16, 256, 0, stream>>>((const char*)ht, ptr, cnt, sorted, a, out, N, use_rank);
}

// Round 8
// 193.650 us; speedup vs baseline: 1.0625x; 1.0625x over previous
//
#include <hip/hip_runtime.h>
#include <hip/hip_fp16.h>
#include <cstdint>

#define D 128
#define BLK 256

constexpr float MINN    = 1e-15f;
constexpr float ATCLIP  = 1.0f - 1e-7f;
constexpr float BALLEPS = 4e-3f;

typedef _Float16 f16x8 __attribute__((ext_vector_type(8)));
typedef float    f32x4 __attribute__((ext_vector_type(4)));

union H4 { _Float16 h[4]; uint2 u2; };
union H8 { _Float16 h[8]; uint4 u4; };

typedef __attribute__((address_space(1))) const void gas_v;
typedef __attribute__((address_space(3))) void las_v;

__device__ __forceinline__ float red64(float v) {
    v += __shfl_xor(v, 1, 64);
    v += __shfl_xor(v, 2, 64);
    v += __shfl_xor(v, 4, 64);
    v += __shfl_xor(v, 8, 64);
    v += __shfl_xor(v, 16, 64);
    v += __shfl_xor(v, 32, 64);
    return v;
}

__device__ __forceinline__ int red64i(int v) {
    v += __shfl_xor(v, 1, 64);
    v += __shfl_xor(v, 2, 64);
    v += __shfl_xor(v, 4, 64);
    v += __shfl_xor(v, 8, 64);
    v += __shfl_xor(v, 16, 64);
    v += __shfl_xor(v, 32, 64);
    return v;
}

__device__ __forceinline__ float red16(float v) {
    v += __shfl_xor(v, 1, 64);
    v += __shfl_xor(v, 2, 64);
    v += __shfl_xor(v, 4, 64);
    v += __shfl_xor(v, 8, 64);
    return v;
}

// fast transcendentals (args here are small: |x| < ~16)
__device__ __forceinline__ float tanh_fast(float x) {   // x >= 0
    float e = __expf(2.f * fminf(x, 15.f));
    return __fdividef(e - 1.f, e + 1.f);
}
__device__ __forceinline__ float artanh_fast(float x) { // x in [0, 1)
    x = fminf(x, ATCLIP);
    return 0.5f * __logf(__fdividef(1.f + x, 1.f - x));
}

// ---------------------------------------------------------------------------
// Kernel 0: blocks 0..7  : W fp32 -> fp16, fragment-order layout.
//           blocks 8..   : zero cnt[] + lookback[] region.
// Wh[f*1024 + r*8 + j] = (fp16) W[r][f*8+j],  f = k-chunk 0..15, r = row 0..127.
// ---------------------------------------------------------------------------
__global__ __launch_bounds__(256) void k_prep(const float* __restrict__ W,
                                              _Float16* __restrict__ Wh,
                                              int* __restrict__ zero, int zeroInts)
{
    const int t = threadIdx.x;
    const int bid = blockIdx.x;
    if (bid < 8) {
        int i = bid * 256 + t;                // 0..2047
        int f = i >> 7;
        int r = i & 127;
        const float4* src = (const float4*)(W + r * 128 + f * 8);
        float4 v0 = src[0], v1 = src[1];
        H8 u;
        u.h[0] = (_Float16)v0.x; u.h[1] = (_Float16)v0.y;
        u.h[2] = (_Float16)v0.z; u.h[3] = (_Float16)v0.w;
        u.h[4] = (_Float16)v1.x; u.h[5] = (_Float16)v1.y;
        u.h[6] = (_Float16)v1.z; u.h[7] = (_Float16)v1.w;
        *(uint4*)(Wh + i * 8) = u.u4;
    } else {
        int i = (bid - 8) * 256 + t;          // int4 index
        int base = i * 4;
        if (base + 3 < zeroInts) {
            *(int4*)(zero + base) = make_int4(0, 0, 0, 0);
        } else if (base < zeroInts) {
            for (int k = base; k < zeroInts; ++k) zero[k] = 0;
        }
    }
}

// ---------------------------------------------------------------------------
// Kernel 1 (MFMA): h_t = logmap0( mobius_add( mobius_matvec(W,x), expmap0(b) ) )
// EXACT r1 structure (best measured: 41.5 us, VGPR 80, total 191.9):
// 64 nodes/block, 4 waves. x staged fp32 via async global_load_lds (width=16)
// with XOR-swizzled 16B chunks. LDS exactly 32 KB -> 5 blocks/CU.
// p = expmap0(b) = bscale*b folded analytically (b re-read from L1).
// In-degree histogram at the TAIL, operand loads IN the tail (lean register
// state — r4/r7 proved any cross-body register preload costs occupancy).
// ---------------------------------------------------------------------------
__global__ __launch_bounds__(BLK) void k_node_mfma(
    const float* __restrict__ x, const _Float16* __restrict__ Wh,
    const float* __restrict__ b, uint2* __restrict__ ht, int N,
    const int* __restrict__ ei, int* __restrict__ cnt,
    int* __restrict__ rank, int E, int eslice, int use_rank)
{
    __shared__ float xs[64 * 128];      // 32768 B fp32, swizzled (overlaid later)

    const int t     = threadIdx.x;
    const int node0 = blockIdx.x * 64;
    const int lane  = t & 63;
    const int w     = t >> 6;

    // ---- async DMA: x -> LDS (8 x 1KB per wave, fire-and-forget)
#pragma unroll
    for (int i = 0; i < 8; ++i) {
        int P      = (w * 8 + i) * 64 + lane;       // LDS chunk slot 0..2047
        int node   = P >> 5;
        int q      = (P & 31) ^ (node & 7);         // swizzle: slot p holds chunk p^(n&7)
        int node_g = min(node0 + node, N - 1);      // clamp OOB tail (stores guarded later)
        const float* src = x + (size_t)node_g * 128 + q * 4;
        char* dst = (char*)xs + (size_t)(w * 8 + i) * 1024;   // wave-uniform base
        __builtin_amdgcn_global_load_lds((gas_v*)src, (las_v*)dst, 16, 0, 0);
    }

    // ---- bscale for p = expmap0(b) = bscale*b : wave-wide reduction
    float2 b2 = ((const float2*)b)[lane];     // 64 lanes x 2 = all 128 dims
    float pb  = fmaf(b2.x, b2.x, b2.y * b2.y);
    float bn2 = red64(pb);
    float bnc    = fmaxf(sqrtf(bn2), MINN);
    float bscale = __fdividef(tanh_fast(bnc), bnc);
    const float y2 = bscale * bscale * bn2;   // ||p||^2
    __syncthreads();                          // drains DMA (vmcnt): xs ready

    // ---- MFMA: mx[128 out][16 nodes] per wave
    const int c = lane & 15;        // node within wave-tile / W row within m-tile
    const int g = lane >> 4;        // quad

    f32x4 Cf[8];
#pragma unroll
    for (int mt = 0; mt < 8; ++mt) Cf[mt] = (f32x4){0.f, 0.f, 0.f, 0.f};

    const int bnode = w * 16 + c;
    const int sw    = bnode & 7;
    const float* xrow = &xs[bnode * 128];
    float px = 0.f;                 // fp32 ||x||^2 partial (this lane's 32 dims)

#pragma unroll
    for (int s = 0; s < 4; ++s) {
        int q0 = s * 8 + g * 2;
        f32x4 lo = *(const f32x4*)&xrow[(q0 ^ sw) * 4];
        f32x4 hi = *(const f32x4*)&xrow[((q0 + 1) ^ sw) * 4];
        px = fmaf(lo[0], lo[0], px); px = fmaf(lo[1], lo[1], px);
        px = fmaf(lo[2], lo[2], px); px = fmaf(lo[3], lo[3], px);
        px = fmaf(hi[0], hi[0], px); px = fmaf(hi[1], hi[1], px);
        px = fmaf(hi[2], hi[2], px); px = fmaf(hi[3], hi[3], px);
        f16x8 Bf;
        Bf[0] = (_Float16)lo[0]; Bf[1] = (_Float16)lo[1];
        Bf[2] = (_Float16)lo[2]; Bf[3] = (_Float16)lo[3];
        Bf[4] = (_Float16)hi[0]; Bf[5] = (_Float16)hi[1];
        Bf[6] = (_Float16)hi[2]; Bf[7] = (_Float16)hi[3];
        const _Float16* wp = Wh + ((s * 4 + g) << 10) + (c << 3);
#pragma unroll
        for (int mt = 0; mt < 8; ++mt) {
            f16x8 Af = *(const f16x8*)&wp[mt << 7];
            Cf[mt] = __builtin_amdgcn_mfma_f32_16x16x32_f16(Af, Bf, Cf[mt], 0, 0, 0);
        }
    }
    // lane holds mx[mt*16 + g*4 + r][node0 + w*16 + c] in Cf[mt][r]

    // ---- per-node epilogue (4 lanes per node via quads)
    // p = bscale*b, so <mx,p> = bscale * <mx,b>: accumulate against b (L1-hot)
    const float4* b4 = (const float4*)b;
    float pm = 0.f, pdb = 0.f;
#pragma unroll
    for (int mt = 0; mt < 8; ++mt) {
        float4 bv = b4[mt * 4 + g];
        pm  = fmaf(Cf[mt][0], Cf[mt][0], pm);
        pm  = fmaf(Cf[mt][1], Cf[mt][1], pm);
        pm  = fmaf(Cf[mt][2], Cf[mt][2], pm);
        pm  = fmaf(Cf[mt][3], Cf[mt][3], pm);
        pdb = fmaf(Cf[mt][0], bv.x, pdb);
        pdb = fmaf(Cf[mt][1], bv.y, pdb);
        pdb = fmaf(Cf[mt][2], bv.z, pdb);
        pdb = fmaf(Cf[mt][3], bv.w, pdb);
    }
    float xn2 = px;
    xn2 += __shfl_xor(xn2, 16); xn2 += __shfl_xor(xn2, 32);   // ||x||^2 (exact fp32)
    pm  += __shfl_xor(pm, 16);  pm  += __shfl_xor(pm, 32);    // ||mx||^2
    pdb += __shfl_xor(pdb, 16); pdb += __shfl_xor(pdb, 32);   // <mx, b>
    float pd = bscale * pdb;                                  // <mx, p>

    float xn      = fmaxf(sqrtf(xn2), MINN);
    float mxn_raw = sqrtf(pm);
    float mxn     = fmaxf(mxn_raw, MINN);
    float alpha   = __fdividef(tanh_fast(__fdividef(mxn, xn) * artanh_fast(xn)), mxn);
    if (mxn_raw <= 1e-10f) alpha = 0.f;     // zero-row guard

    float x2  = alpha * alpha * pm;
    float xy  = alpha * pd;
    float den = fmaxf(fmaf(x2, y2, 1.f + 2.f * xy), MINN);
    float ca  = __fdividef((1.f + 2.f * xy + y2) * alpha, den);
    float cb  = __fdividef(1.f - x2, den);

    // ||h||^2 analytically: h = ca*mx + cb*p
    float hn2 = ca * ca * pm + 2.f * ca * cb * pd + cb * cb * y2;
    float hn  = fmaxf(sqrtf(hn2), MINN);
    float lsc = __fdividef(artanh_fast(hn), hn);
    float s1  = lsc * ca;
    float s2b = lsc * cb * bscale;          // scale applied directly to b

    // ---- pack to fp16 via LDS transpose (overlay own wave's dead x slice;
    // wave-private region, LDS ops in-order within a wave -> no barrier needed)
    uint2* lout = (uint2*)((char*)xs + (size_t)w * 8192);
#pragma unroll
    for (int mt = 0; mt < 8; ++mt) {
        float4 bv = b4[mt * 4 + g];
        H4 u;
        u.h[0] = (_Float16)fmaf(s1, Cf[mt][0], s2b * bv.x);
        u.h[1] = (_Float16)fmaf(s1, Cf[mt][1], s2b * bv.y);
        u.h[2] = (_Float16)fmaf(s1, Cf[mt][2], s2b * bv.z);
        u.h[3] = (_Float16)fmaf(s1, Cf[mt][3], s2b * bv.w);
        lout[c * 33 + mt * 4 + g] = u.u2;   // col = mt*4+g holds dims 4col..4col+3
    }
    __syncthreads();

    // ---- coalesced copy-out
    for (int it = 0; it < 8; ++it) {
        int lin  = it * BLK + t;        // 2048 uint2
        int node = lin >> 5;
        int col  = lin & 31;
        int gn   = node0 + node;
        if (gn < N) {
            const uint2* lsrc = (const uint2*)((const char*)xs + (size_t)(node >> 4) * 8192);
            ht[(size_t)gn * 32 + col] = lsrc[(node & 15) * 33 + col];
        }
    }

    // ---- in-degree histogram at the TAIL: no barrier follows; atomics
    // overlap other blocks' compute/retirement. Lean register state.
    {
        int e0 = blockIdx.x * eslice;
        if (use_rank) {
            for (int i = t; i < eslice; i += BLK) {
                int e = e0 + i;
                if (e < E) rank[e] = atomicAdd(&cnt[ei[E + e]], 1);
            }
        } else {
            for (int i = t; i < eslice; i += BLK) {
                int e = e0 + i;
                if (e < E) atomicAdd(&cnt[ei[E + e]], 1);
            }
        }
    }
}

// ---------------------------------------------------------------------------
// Single-pass scan with parallel decoupled lookback: ptr[n] = global exclusive
// prefix of cnt. lb[bid] = (flag<<32)|value; flag 1 = aggregate, 2 = inclusive
// prefix. All blocks co-resident (nc ~ 98 << CU count); wave 3 does a 64-wide
// parallel lookback. Agent-scope atomics for cross-XCD safety.
// ---------------------------------------------------------------------------
__global__ __launch_bounds__(256) void k_scan(
    const int* __restrict__ cnt, int* __restrict__ ptr,
    unsigned long long* __restrict__ lb, int N)
{
    __shared__ int s[256];
    __shared__ int sbase;
    const int t   = threadIdx.x;
    const int bid = blockIdx.x;
    const int lane = t & 63;
    const int w    = t >> 6;

    int base = bid * 1024 + t * 4;
    int v0 = 0, v1 = 0, v2 = 0, v3 = 0;
    if (base + 3 < N) {
        int4 q = *(const int4*)&cnt[base];
        v0 = q.x; v1 = q.y; v2 = q.z; v3 = q.w;
    } else {
        if (base + 0 < N) v0 = cnt[base + 0];
        if (base + 1 < N) v1 = cnt[base + 1];
        if (base + 2 < N) v2 = cnt[base + 2];
        if (base + 3 < N) v3 = cnt[base + 3];
    }
    int sum = v0 + v1 + v2 + v3;
    s[t] = sum;
    __syncthreads();
    for (int off = 1; off < 256; off <<= 1) {
        int xv = (t >= off) ? s[t - off] : 0;
        __syncthreads();
        s[t] += xv;
        __syncthreads();
    }
    int excl  = s[t] - sum;
    int total = s[255];

    // publish own aggregate (block 0 publishes its inclusive prefix directly)
    if (t == 255) {
        unsigned long long pkt =
            ((unsigned long long)((bid == 0) ? 2u : 1u) << 32) | (unsigned)total;
        __hip_atomic_store(&lb[bid], pkt, __ATOMIC_RELEASE, __HIP_MEMORY_SCOPE_AGENT);
        if (bid == 0) sbase = 0;
    }

    // wave 3: parallel lookback
    if (bid > 0 && w == 3) {
        int exclb = 0;
        int j = bid - 1;
        while (true) {
            int idx = j - lane;
            unsigned f = 0; int v = 0;
            if (idx >= 0) {
                unsigned long long p;
                do {
                    p = __hip_atomic_load(&lb[idx], __ATOMIC_ACQUIRE, __HIP_MEMORY_SCOPE_AGENT);
                    f = (unsigned)(p >> 32);
                } while (f == 0);
                v = (int)(unsigned)(p & 0xffffffffu);
            }
            unsigned long long m2 = __ballot(f == 2u);
            if (m2) {
                int Lstop = __ffsll((long long)m2) - 1;   // nearest flag-2 predecessor
                int contrib = (lane <= Lstop) ? v : 0;
                exclb += red64i(contrib);
                break;
            } else {
                exclb += red64i((idx >= 0) ? v : 0);
                j -= 64;
            }
        }
        if (lane == 0) {
            unsigned long long pkt2 =
                ((unsigned long long)2u << 32) | (unsigned)(exclb + total);
            __hip_atomic_store(&lb[bid], pkt2, __ATOMIC_RELEASE, __HIP_MEMORY_SCOPE_AGENT);
            sbase = exclb;
        }
    }
    __syncthreads();

    int r = excl + sbase;
    if (base + 0 < N) ptr[base + 0] = r; r += v0;
    if (base + 1 < N) ptr[base + 1] = r; r += v1;
    if (base + 2 < N) ptr[base + 2] = r; r += v2;
    if (base + 3 < N) ptr[base + 3] = r;
}

// scatter, rank-based (no atomics): pos = global excl start + per-edge rank.
// ptr stays pristine (exclusive). Normal stores: sorted IS re-read by agg,
// keep it L2-resident (r7's nontemporal store here was wrong).
__global__ __launch_bounds__(256) void k_scatter_rank(
    const int* __restrict__ ei, const float* __restrict__ ew,
    const int* __restrict__ ptr, const int* __restrict__ rank,
    int2* __restrict__ sorted, int E)
{
    int e = blockIdx.x * 256 + threadIdx.x;
    if (e >= E) return;
    int src = ei[e];
    int dst = ei[E + e];
    float w = ew[e];
    int pos = ptr[dst] + rank[e];
    sorted[pos] = make_int2(src << 8, __float_as_int(w));
}

// fallback scatter with atomics (destroys ptr -> ptr becomes inclusive end)
__global__ __launch_bounds__(256) void k_scatter_atomic(
    const int* __restrict__ ei, const float* __restrict__ ew,
    int* __restrict__ ptr, int2* __restrict__ sorted, int E)
{
    int e = blockIdx.x * 256 + threadIdx.x;
    if (e >= E) return;
    int src = ei[e];
    int dst = ei[E + e];
    float w = ew[e];
    int pos = atomicAdd(&ptr[dst], 1);
    sorted[pos] = make_int2(src << 8, __float_as_int(w));
}

// ---------------------------------------------------------------------------
// Fused aggregation + epilogue: 16 lanes per node (4 nodes per wave64).
// Lane owns dims 8*li .. 8*li+7 (uint4 = 16 B per gathered row).
// 4-edge unrolled gather for memory-level parallelism. Nontemporal stores
// ONLY for out (never re-read).
// rmode=1: ptr is exclusive start (rank path). rmode=0: ptr is inclusive end.
// ---------------------------------------------------------------------------
__global__ __launch_bounds__(256) void k_agg_final(
    const char* __restrict__ htb, const int* __restrict__ ptr,
    const int* __restrict__ cnt, const int2* __restrict__ sorted,
    const float* __restrict__ a_in, float* __restrict__ out, int N, int rmode)
{
    const int t   = threadIdx.x;
    const int li  = t & 15;          // lane within 16-lane group
    const int grp = t >> 4;          // group within block (0..15)
    const int n   = blockIdx.x * 16 + grp;
    if (n >= N) return;
    const float a = a_in[0];

    H8 own; own.u4 = *(const uint4*)(htb + (size_t)n * 256 + li * 16);
    float acc[8];
#pragma unroll
    for (int k = 0; k < 8; ++k) acc[k] = (float)own.h[k];

    int basep = ptr[n];
    int cn    = cnt[n];
    int s0    = rmode ? basep : basep - cn;
    int e0    = s0 + cn;

    const int lioff = li * 16;
    int j = s0;
    for (; j + 4 <= e0; j += 4) {
        int2 d0 = sorted[j];
        int2 d1 = sorted[j + 1];
        int2 d2 = sorted[j + 2];
        int2 d3 = sorted[j + 3];
        H8 g0, g1, g2, g3;
        g0.u4 = *(const uint4*)(htb + (unsigned)d0.x + lioff);
        g1.u4 = *(const uint4*)(htb + (unsigned)d1.x + lioff);
        g2.u4 = *(const uint4*)(htb + (unsigned)d2.x + lioff);
        g3.u4 = *(const uint4*)(htb + (unsigned)d3.x + lioff);
        float w0 = __int_as_float(d0.y);
        float w1 = __int_as_float(d1.y);
        float w2 = __int_as_float(d2.y);
        float w3 = __int_as_float(d3.y);
#pragma unroll
        for (int k = 0; k < 8; ++k) acc[k] = fmaf((float)g0.h[k], w0, acc[k]);
#pragma unroll
        for (int k = 0; k < 8; ++k) acc[k] = fmaf((float)g1.h[k], w1, acc[k]);
#pragma unroll
        for (int k = 0; k < 8; ++k) acc[k] = fmaf((float)g2.h[k], w2, acc[k]);
#pragma unroll
        for (int k = 0; k < 8; ++k) acc[k] = fmaf((float)g3.h[k], w3, acc[k]);
    }
    for (; j < e0; ++j) {
        int2 d = sorted[j];
        H8 g; g.u4 = *(const uint4*)(htb + (unsigned)d.x + lioff);
        float w = __int_as_float(d.y);
#pragma unroll
        for (int k = 0; k < 8; ++k) acc[k] = fmaf((float)g.h[k], w, acc[k]);
    }

    // h2_t = acc; PReLU
    float pv = 0.f;
#pragma unroll
    for (int k = 0; k < 8; ++k) {
        float v = acc[k];
        v = (v >= 0.f) ? v : a * v;
        acc[k] = v;
        pv = fmaf(v, v, pv);
    }
    float m2 = red16(pv);
    float rc = fmaxf(sqrtf(m2), MINN);
    float te = tanh_fast(rc);
    const float maxn = 1.0f - BALLEPS;
    float fsc = __fdividef(fminf(fmaxf(te, MINN), maxn), rc);

    f32x4 o0 = {fsc * acc[0], fsc * acc[1], fsc * acc[2], fsc * acc[3]};
    f32x4 o1 = {fsc * acc[4], fsc * acc[5], fsc * acc[6], fsc * acc[7]};
    f32x4* orow = (f32x4*)(out + (size_t)n * D);
    __builtin_nontemporal_store(o0, &orow[li * 2 + 0]);
    __builtin_nontemporal_store(o1, &orow[li * 2 + 1]);
}

// ---------------------------------------------------------------------------
extern "C" void kernel_launch(void* const* d_in, const int* in_sizes, int n_in,
                              void* d_out, int out_size, void* d_ws, size_t ws_size,
                              hipStream_t stream)
{
    const float* x  = (const float*)d_in[0];
    const int*   ei = (const int*)  d_in[1];
    const float* ew = (const float*)d_in[2];
    const float* W  = (const float*)d_in[3];
    const float* b  = (const float*)d_in[4];
    const float* a  = (const float*)d_in[5];
    float* out = (float*)d_out;

    const int N = in_sizes[0] / D;
    const int E = in_sizes[1] / 2;
    const int nc = (N + 1023) / 1024;

    // workspace carve-up
    char* ws = (char*)d_ws;
    size_t HT_B       = (size_t)N * D * 2;          // fp16 h_t
    uint2*              ht  = (uint2*)ws;
    size_t off_cnt    = HT_B;
    int*                cnt = (int*)(ws + off_cnt);
    size_t off_lb     = (off_cnt + (size_t)N * 4 + 15) & ~(size_t)15;
    unsigned long long* lb  = (unsigned long long*)(ws + off_lb);
    size_t off_ptr    = (off_lb + (size_t)nc * 8 + 15) & ~(size_t)15;
    int*                ptr = (int*)(ws + off_ptr);
    size_t off_sorted = (off_ptr + (size_t)N * 4 + 15) & ~(size_t)15;
    int2*               sorted = (int2*)(ws + off_sorted);
    size_t off_wh     = off_sorted + (size_t)E * 8;
    _Float16*           Wh  = (_Float16*)(ws + off_wh);
    size_t off_rank   = off_wh + 32768;
    int*                rank = (int*)(ws + off_rank);
    int use_rank = (ws_size >= off_rank + (size_t)E * 4) ? 1 : 0;

    int zeroInts = (int)((off_ptr - off_cnt) / 4);   // cnt + lb (+pad)
    int zb  = ((zeroInts + 3) / 4 + 255) / 256;
    int nb1 = (N + 63) / 64;                         // 64 nodes / block (r1 grid)
    int eslice = (E + nb1 - 1) / nb1;

    k_prep<<<8 + zb, 256, 0, stream>>>(W, Wh, cnt, zeroInts);
    k_node_mfma<<<nb1, BLK, 0, stream>>>(x, Wh, b, ht, N, ei, cnt,
                                         use_rank ? rank : nullptr, E, eslice, use_rank);
    k_scan<<<nc, 256, 0, stream>>>(cnt, ptr, lb, N);
    if (use_rank)
        k_scatter_rank<<<(E + 255) / 256, 256, 0, stream>>>(ei, ew, ptr, rank, sorted, E);
    else
        k_scatter_atomic<<<(E + 255) / 256, 256, 0, stream>>>(ei, ew, ptr, sorted, E);
    k_agg_final<<<(N + 15) / 16, 256, 0, stream>>>((const char*)ht, ptr, cnt, sorted, a, out, N, use_rank);
}